// Round 14
// baseline (226.982 us; speedup 1.0000x reference)
//
#include <hip/hip_runtime.h>
#include <cstdint>
#include <cstddef>

#define CC 128
#define LOG_FINE 7
#define FINE 128
#define CAPE 6144     // capacity per edge bucket (mean 4092, std ~64)
#define CAPV 3072     // capacity per node bucket (mean 2046, std ~45)
#define BIN_TILE 4096 // pairs per bin block (512 threads x 8)

typedef __attribute__((ext_vector_type(8))) short bf16x8;
typedef __attribute__((ext_vector_type(4))) float f32x4;

__device__ __forceinline__ unsigned f2b(float f) {
    const unsigned u = __float_as_uint(f);
    return (u + 0x7fffu + ((u >> 16) & 1u)) >> 16;
}
__device__ __forceinline__ float b2f_lo(unsigned u) { return __uint_as_float(u << 16); }
__device__ __forceinline__ float b2f_hi(unsigned u) { return __uint_as_float(u & 0xffff0000u); }

// ---- prep: [0,nbin) bin pairs; [nbin,nbin+ncvt) f32->bf16 convert; last 4 blocks: W B-frags ----
__global__ __launch_bounds__(512) void prep(const int* __restrict__ nidx,
                                            const int* __restrict__ eidx,
                                            int* __restrict__ curE,
                                            int* __restrict__ curV,
                                            unsigned* __restrict__ binnedE,
                                            unsigned* __restrict__ binnedV,
                                            int nnz, int nbE, int nbV, int nbin, int ncvt,
                                            const float4* __restrict__ xin,
                                            uint2* __restrict__ xh, int n4,
                                            const float* __restrict__ W,
                                            uint4* __restrict__ Bfrag) {
    __shared__ int cntE[512], gposE[512];
    __shared__ int cntV[1024], gposV[1024];
    const int tid = threadIdx.x;
    if (blockIdx.x >= (unsigned)(nbin + ncvt)) {
        // -------- B-fragment path (4 blocks x 512 = 2048) --------
        const int idx = (blockIdx.x - nbin - ncvt) * 512 + tid;
        if (idx < 2048) {
            const int lane = idx & 63, t = idx >> 6;
            const int kk = t >> 3, nt = t & 7;
            const int k0 = kk * 32 + (lane >> 4) * 8;
            const int n = nt * 16 + (lane & 15);
            unsigned r[4];
#pragma unroll
            for (int p = 0; p < 4; ++p) {
                const float w0 = W[(size_t)(k0 + 2 * p) * CC + n];
                const float w1 = W[(size_t)(k0 + 2 * p + 1) * CC + n];
                r[p] = f2b(w0) | (f2b(w1) << 16);
            }
            Bfrag[idx] = make_uint4(r[0], r[1], r[2], r[3]);
        }
        return;
    }
    if (blockIdx.x >= (unsigned)nbin) {
        // -------- convert path --------
        const int bid = blockIdx.x - nbin;
        for (int i = bid * 512 + tid; i < n4; i += ncvt * 512) {
            const float4 v = xin[i];
            xh[i] = make_uint2(f2b(v.x) | (f2b(v.y) << 16), f2b(v.z) | (f2b(v.w) << 16));
        }
        return;
    }
    // -------- bin path --------
    for (int i = tid; i < nbE; i += 512) cntE[i] = 0;
    for (int i = tid; i < nbV; i += 512) cntV[i] = 0;
    __syncthreads();
    const int base = blockIdx.x * BIN_TILE;
    int pE[8], rE[8], pV[8], rV[8];
#pragma unroll
    for (int j = 0; j < 8; ++j) {
        const int i = base + tid + j * 512;
        if (i < nnz) {
            const int e = eidx[i], v = nidx[i];
            const int bE = e >> LOG_FINE, bV = v >> LOG_FINE;
            rE[j] = (bE << 16) | atomicAdd(&cntE[bE], 1);
            pE[j] = (v << LOG_FINE) | (e & (FINE - 1));
            rV[j] = (bV << 16) | atomicAdd(&cntV[bV], 1);
            pV[j] = (e << LOG_FINE) | (v & (FINE - 1));
        } else { rE[j] = -1; rV[j] = -1; }
    }
    __syncthreads();
    for (int i = tid; i < nbE; i += 512) {
        const int c = cntE[i];
        gposE[i] = (c > 0) ? atomicAdd(&curE[i], c) : 0;
    }
    for (int i = tid; i < nbV; i += 512) {
        const int c = cntV[i];
        gposV[i] = (c > 0) ? atomicAdd(&curV[i], c) : 0;
    }
    __syncthreads();
#pragma unroll
    for (int j = 0; j < 8; ++j) {
        if (rE[j] >= 0) {
            const int b = rE[j] >> 16;
            binnedE[(size_t)b * CAPE + gposE[b] + (rE[j] & 0xffff)] = (unsigned)pE[j];
        }
        if (rV[j] >= 0) {
            const int b = rV[j] >> 16;
            binnedV[(size_t)b * CAPV + gposV[b] + (rV[j] & 0xffff)] = (unsigned)pV[j];
        }
    }
}

// ---- merged per-bucket counting-sort: blocks [0,nbE)=E side; [nbE,nbE+nbV)=V side (+Dinv) ----
__global__ __launch_bounds__(512) void fill_all(const int* __restrict__ curE,
                                                const int* __restrict__ curV,
                                                unsigned* __restrict__ binnedE,
                                                unsigned* __restrict__ binnedV,
                                                const float* __restrict__ hw,
                                                int2* __restrict__ rowsE,
                                                int2* __restrict__ rowsV,
                                                float* __restrict__ Dinv,
                                                int E, int N, int nbE) {
    __shared__ unsigned vals[CAPE];
    __shared__ int scnt[FINE], soff[FINE], sscan[FINE];
    __shared__ float sd[FINE];
    const int tid = threadIdx.x;
    const bool isE = (blockIdx.x < (unsigned)nbE);
    const int b = isE ? blockIdx.x : blockIdx.x - nbE;
    const int cap = isE ? CAPE : CAPV;
    const int base = b * cap;
    const int cnt = isE ? curE[b] : curV[b];   // relative cursor == count
    unsigned* binned = isE ? binnedE : binnedV;
    int2* rows = isE ? rowsE : rowsV;
    const int nrows = isE ? E : N;
    for (int i = tid; i < cnt; i += 512) vals[i] = binned[base + i];
    if (tid < FINE) { scnt[tid] = 0; sd[tid] = 0.f; }
    __syncthreads();
    for (int i = tid; i < cnt; i += 512) atomicAdd(&scnt[vals[i] & (FINE - 1)], 1);
    __syncthreads();
    if (tid < FINE) sscan[tid] = scnt[tid];
    __syncthreads();
#pragma unroll
    for (int d = 1; d < FINE; d <<= 1) {
        int t = 0;
        if (tid >= d && tid < FINE) t = sscan[tid - d];
        __syncthreads();
        if (tid < FINE) sscan[tid] += t;
        __syncthreads();
    }
    if (tid < FINE) {
        const int excl = sscan[tid] - scnt[tid];
        soff[tid] = excl;
        const int row = (b << LOG_FINE) + tid;
        if (row < nrows) rows[row] = make_int2(base + excl, base + excl + scnt[tid]);
    }
    __syncthreads();
    if (isE) {
        for (int i = tid; i < cnt; i += 512) {
            const unsigned p = vals[i];
            const int slot = (int)(p & (FINE - 1));
            const int pos = base + atomicAdd(&soff[slot], 1);
            binned[pos] = p >> LOG_FINE;
        }
    } else {
        for (int i = tid; i < cnt; i += 512) {
            const unsigned p = vals[i];
            const int slot = (int)(p & (FINE - 1));
            const int e = (int)(p >> LOG_FINE);
            const int pos = base + atomicAdd(&soff[slot], 1);
            binned[pos] = (unsigned)e;
            atomicAdd(&sd[slot], hw[e]);
        }
        __syncthreads();
        if (tid < FINE) {
            const int row = (b << LOG_FINE) + tid;
            if (row < N) {
                const float d = sd[tid];
                Dinv[row] = (d > 0.f) ? 1.f / d : 0.f;
            }
        }
    }
}

// ---- hop1: eraw[e,:] = (1/|e|) * sum_{v in e} xh[v,:]; 16 lanes/row, uint4, one-shot ----
__global__ __launch_bounds__(256) void gather_n2e(const int2* __restrict__ rows,
                                                  const unsigned* __restrict__ lst,
                                                  const uint4* __restrict__ xh4,
                                                  uint4* __restrict__ eraw4, int E) {
    const int sub = threadIdx.x >> 5;
    const int half = (threadIdx.x >> 4) & 1;
    const int q = threadIdx.x & 15;
    const int e = blockIdx.x * 8 + sub;
    if (e >= E) return;
    const int2 st = rows[e];
    const int s = st.x, t = st.y;
    float a[8];
#pragma unroll
    for (int k = 0; k < 8; ++k) a[k] = 0.f;
    int j = s;
    for (; j + 7 < t; j += 8) {
        const int v0 = (int)lst[j + 0 + half];
        const int v1 = (int)lst[j + 2 + half];
        const int v2 = (int)lst[j + 4 + half];
        const int v3 = (int)lst[j + 6 + half];
        const uint4 u0 = xh4[(size_t)v0 * 16 + q];
        const uint4 u1 = xh4[(size_t)v1 * 16 + q];
        const uint4 u2 = xh4[(size_t)v2 * 16 + q];
        const uint4 u3 = xh4[(size_t)v3 * 16 + q];
        a[0] += b2f_lo(u0.x) + b2f_lo(u1.x) + b2f_lo(u2.x) + b2f_lo(u3.x);
        a[1] += b2f_hi(u0.x) + b2f_hi(u1.x) + b2f_hi(u2.x) + b2f_hi(u3.x);
        a[2] += b2f_lo(u0.y) + b2f_lo(u1.y) + b2f_lo(u2.y) + b2f_lo(u3.y);
        a[3] += b2f_hi(u0.y) + b2f_hi(u1.y) + b2f_hi(u2.y) + b2f_hi(u3.y);
        a[4] += b2f_lo(u0.z) + b2f_lo(u1.z) + b2f_lo(u2.z) + b2f_lo(u3.z);
        a[5] += b2f_hi(u0.z) + b2f_hi(u1.z) + b2f_hi(u2.z) + b2f_hi(u3.z);
        a[6] += b2f_lo(u0.w) + b2f_lo(u1.w) + b2f_lo(u2.w) + b2f_lo(u3.w);
        a[7] += b2f_hi(u0.w) + b2f_hi(u1.w) + b2f_hi(u2.w) + b2f_hi(u3.w);
    }
    for (; j + 1 < t; j += 2) {
        const int v0 = (int)lst[j + half];
        const uint4 u = xh4[(size_t)v0 * 16 + q];
        a[0] += b2f_lo(u.x); a[1] += b2f_hi(u.x);
        a[2] += b2f_lo(u.y); a[3] += b2f_hi(u.y);
        a[4] += b2f_lo(u.z); a[5] += b2f_hi(u.z);
        a[6] += b2f_lo(u.w); a[7] += b2f_hi(u.w);
    }
    if (j < t && half == 0) {
        const uint4 u = xh4[(size_t)lst[j] * 16 + q];
        a[0] += b2f_lo(u.x); a[1] += b2f_hi(u.x);
        a[2] += b2f_lo(u.y); a[3] += b2f_hi(u.y);
        a[4] += b2f_lo(u.z); a[5] += b2f_hi(u.z);
        a[6] += b2f_lo(u.w); a[7] += b2f_hi(u.w);
    }
#pragma unroll
    for (int k = 0; k < 8; ++k) a[k] += __shfl_xor(a[k], 16);
    if (half == 0) {
        const float binv = (t > s) ? 1.f / (float)(t - s) : 0.f;
#pragma unroll
        for (int k = 0; k < 8; ++k) a[k] *= binv;
        uint4 o;
        o.x = f2b(a[0]) | (f2b(a[1]) << 16);
        o.y = f2b(a[2]) | (f2b(a[3]) << 16);
        o.z = f2b(a[4]) | (f2b(a[5]) << 16);
        o.w = f2b(a[6]) | (f2b(a[7]) << 16);
        eraw4[(size_t)e * 16 + q] = o;
    }
}

// ---- mm via MFMA: efeat[M,128](bf16) = eraw[M,128](bf16) @ W (B-frags precomputed) ----
__global__ __launch_bounds__(256) void mm_mfma(const uint4* __restrict__ A4,
                                               const uint4* __restrict__ Bfrag,
                                               unsigned short* __restrict__ Out, int M) {
    const int lane = threadIdx.x & 63;
    const int wave = threadIdx.x >> 6;
    const int row0 = blockIdx.x * 64 + wave * 16;
    const int g = lane >> 4;
    const int c = lane & 15;
    const int arow = row0 + c;
    uint4 a[4];
#pragma unroll
    for (int kk = 0; kk < 4; ++kk) {
        a[kk] = (arow < M) ? A4[(size_t)arow * 16 + kk * 4 + g]
                           : make_uint4(0u, 0u, 0u, 0u);
    }
    f32x4 acc[8];
#pragma unroll
    for (int nt = 0; nt < 8; ++nt) acc[nt] = (f32x4){0.f, 0.f, 0.f, 0.f};
#pragma unroll
    for (int nt = 0; nt < 8; ++nt) {
#pragma unroll
        for (int kk = 0; kk < 4; ++kk) {
            const uint4 bv = Bfrag[(kk * 8 + nt) * 64 + lane];
            acc[nt] = __builtin_amdgcn_mfma_f32_16x16x32_bf16(
                *(const bf16x8*)&a[kk], *(const bf16x8*)&bv, acc[nt], 0, 0, 0);
        }
    }
#pragma unroll
    for (int nt = 0; nt < 8; ++nt) {
#pragma unroll
        for (int r = 0; r < 4; ++r) {
            const int row = row0 + g * 4 + r;
            if (row < M) Out[(size_t)row * CC + nt * 16 + c] = (unsigned short)f2b(acc[nt][r]);
        }
    }
}

// ---- hop2 + BN stats: oh[v](bf16) = Dinv*sum efeat + b; LDS slot-owned sums (no atomics) ----
__global__ __launch_bounds__(256) void gather_e2n_bn(const int2* __restrict__ rows,
                                                     const unsigned* __restrict__ lst,
                                                     const uint4* __restrict__ ef4,
                                                     const float* __restrict__ Dinv,
                                                     const float* __restrict__ b,
                                                     uint4* __restrict__ oh,
                                                     float* __restrict__ copies, int N) {
    __shared__ float bl[8][256];   // 8 KB, slot-owned (no LDS atomics)
    const int tid = threadIdx.x;
    for (int i = tid; i < 2048; i += 256) ((float*)bl)[i] = 0.f;
    __syncthreads();
    const int sub = tid >> 5;
    const int half = (tid >> 4) & 1;
    const int q = tid & 15;
    const int v = blockIdx.x * 8 + sub;
    if (v < N) {
        const int2 st = rows[v];
        const int s = st.x, t = st.y;
        float a[8];
#pragma unroll
        for (int k = 0; k < 8; ++k) a[k] = 0.f;
        int j = s;
        for (; j + 7 < t; j += 8) {
            const int e0 = (int)lst[j + 0 + half];
            const int e1 = (int)lst[j + 2 + half];
            const int e2 = (int)lst[j + 4 + half];
            const int e3 = (int)lst[j + 6 + half];
            const uint4 u0 = ef4[(size_t)e0 * 16 + q];
            const uint4 u1 = ef4[(size_t)e1 * 16 + q];
            const uint4 u2 = ef4[(size_t)e2 * 16 + q];
            const uint4 u3 = ef4[(size_t)e3 * 16 + q];
            a[0] += b2f_lo(u0.x) + b2f_lo(u1.x) + b2f_lo(u2.x) + b2f_lo(u3.x);
            a[1] += b2f_hi(u0.x) + b2f_hi(u1.x) + b2f_hi(u2.x) + b2f_hi(u3.x);
            a[2] += b2f_lo(u0.y) + b2f_lo(u1.y) + b2f_lo(u2.y) + b2f_lo(u3.y);
            a[3] += b2f_hi(u0.y) + b2f_hi(u1.y) + b2f_hi(u2.y) + b2f_hi(u3.y);
            a[4] += b2f_lo(u0.z) + b2f_lo(u1.z) + b2f_lo(u2.z) + b2f_lo(u3.z);
            a[5] += b2f_hi(u0.z) + b2f_hi(u1.z) + b2f_hi(u2.z) + b2f_hi(u3.z);
            a[6] += b2f_lo(u0.w) + b2f_lo(u1.w) + b2f_lo(u2.w) + b2f_lo(u3.w);
            a[7] += b2f_hi(u0.w) + b2f_hi(u1.w) + b2f_hi(u2.w) + b2f_hi(u3.w);
        }
        for (; j + 1 < t; j += 2) {
            const int e0 = (int)lst[j + half];
            const uint4 u = ef4[(size_t)e0 * 16 + q];
            a[0] += b2f_lo(u.x); a[1] += b2f_hi(u.x);
            a[2] += b2f_lo(u.y); a[3] += b2f_hi(u.y);
            a[4] += b2f_lo(u.z); a[5] += b2f_hi(u.z);
            a[6] += b2f_lo(u.w); a[7] += b2f_hi(u.w);
        }
        if (j < t && half == 0) {
            const uint4 u = ef4[(size_t)lst[j] * 16 + q];
            a[0] += b2f_lo(u.x); a[1] += b2f_hi(u.x);
            a[2] += b2f_lo(u.y); a[3] += b2f_hi(u.y);
            a[4] += b2f_lo(u.z); a[5] += b2f_hi(u.z);
            a[6] += b2f_lo(u.w); a[7] += b2f_hi(u.w);
        }
#pragma unroll
        for (int k = 0; k < 8; ++k) a[k] += __shfl_xor(a[k], 16);
        if (half == 0) {
            const float dinv = Dinv[v];
            const float4 b0 = *(const float4*)&b[8 * q];
            const float4 b1 = *(const float4*)&b[8 * q + 4];
            float o[8];
            o[0] = a[0] * dinv + b0.x; o[1] = a[1] * dinv + b0.y;
            o[2] = a[2] * dinv + b0.z; o[3] = a[3] * dinv + b0.w;
            o[4] = a[4] * dinv + b1.x; o[5] = a[5] * dinv + b1.y;
            o[6] = a[6] * dinv + b1.z; o[7] = a[7] * dinv + b1.w;
            uint4 ov;
            ov.x = f2b(o[0]) | (f2b(o[1]) << 16);
            ov.y = f2b(o[2]) | (f2b(o[3]) << 16);
            ov.z = f2b(o[4]) | (f2b(o[5]) << 16);
            ov.w = f2b(o[6]) | (f2b(o[7]) << 16);
            oh[(size_t)v * 16 + q] = ov;
            *(float4*)&bl[sub][8 * q]       = make_float4(o[0], o[1], o[2], o[3]);
            *(float4*)&bl[sub][8 * q + 4]   = make_float4(o[4], o[5], o[6], o[7]);
            *(float4*)&bl[sub][128 + 8 * q] = make_float4(o[0] * o[0], o[1] * o[1],
                                                          o[2] * o[2], o[3] * o[3]);
            *(float4*)&bl[sub][132 + 8 * q] = make_float4(o[4] * o[4], o[5] * o[5],
                                                          o[6] * o[6], o[7] * o[7]);
        }
    }
    __syncthreads();
    float s = 0.f;
#pragma unroll
    for (int i = 0; i < 8; ++i) s += bl[i][tid];
    atomicAdd(&copies[(blockIdx.x & 63) * 256 + tid], s);
}

// ---- BN normalize + SiLU: reduce 64 sum-copies, read bf16 pre-BN, write f32 ----
__global__ __launch_bounds__(256) void bn_silu(const uint2* __restrict__ oh2,
                                               const float* __restrict__ copies,
                                               const float* __restrict__ gamma,
                                               const float* __restrict__ beta,
                                               float* __restrict__ out, int N) {
    __shared__ float sl[256];
    const int tid = threadIdx.x;
    float s = 0.f;
#pragma unroll 8
    for (int i = 0; i < 64; ++i) s += copies[i * 256 + tid];
    sl[tid] = s;
    __syncthreads();
    const int sub = tid >> 5;
    const int lane = tid & 31;
    const int c4 = lane * 4;
    const float invN = 1.0f / (float)N;
    float g[4], bb[4];
#pragma unroll
    for (int k = 0; k < 4; ++k) {
        const float mean = sl[c4 + k] * invN;
        float var = sl[128 + c4 + k] * invN - mean * mean;
        var = fmaxf(var, 0.f);
        const float istd = rsqrtf(var + 1e-5f);
        g[k] = gamma[c4 + k] * istd;
        bb[k] = beta[c4 + k] - mean * g[k];
    }
    for (int v = blockIdx.x * 8 + sub; v < N; v += gridDim.x * 8) {
        const uint2 u = oh2[(size_t)v * 32 + lane];
        float y[4];
        y[0] = b2f_lo(u.x); y[1] = b2f_hi(u.x);
        y[2] = b2f_lo(u.y); y[3] = b2f_hi(u.y);
        float4 o;
#pragma unroll
        for (int k = 0; k < 4; ++k) {
            const float z = y[k] * g[k] + bb[k];
            (&o.x)[k] = z / (1.f + __expf(-z));
        }
        *(float4*)&out[(size_t)v * CC + c4] = o;
    }
}

extern "C" void kernel_launch(void* const* d_in, const int* in_sizes, int n_in,
                              void* d_out, int out_size, void* d_ws, size_t ws_size,
                              hipStream_t stream) {
    const float* x     = (const float*)d_in[0];
    const int*   hidx  = (const int*)d_in[1];
    const float* hw    = (const float*)d_in[2];
    const float* W     = (const float*)d_in[3];
    const float* b     = (const float*)d_in[4];
    const float* gamma = (const float*)d_in[5];
    const float* beta  = (const float*)d_in[6];

    const int N   = in_sizes[0] / CC;   // 100000
    const int nnz = in_sizes[1] / 2;    // 1600000
    const int E   = in_sizes[2];        // 50000

    const int* nidx = hidx;
    const int* eidx = hidx + nnz;

    float* out = (float*)d_out;

    const int nbE = (E + FINE - 1) / FINE;   // 391
    const int nbV = (N + FINE - 1) / FINE;   // 782

    unsigned* ws      = (unsigned*)d_ws;
    unsigned* xh      = ws;                              // N*64 uints (bf16 x; reused as oh)
    unsigned* eraw    = xh + (size_t)N * 64;             // E*64
    unsigned* efeat   = eraw + (size_t)E * 64;           // E*64
    int2*     rowsE   = (int2*)(efeat + (size_t)E * 64); // E int2
    int2*     rowsV   = rowsE + E;                       // N int2
    float*    Dinv    = (float*)(rowsV + N);             // N floats
    float*    copies  = Dinv + N;                        // 64*256 floats
    int*      curE    = (int*)(copies + 64 * 256);       // nbE (relative)
    int*      curV    = curE + nbE;                      // nbV (relative)
    unsigned* binnedE = (unsigned*)(curV + nbV);         // nbE*CAPE
    unsigned* binnedV = binnedE + (size_t)nbE * CAPE;    // nbV*CAPV
    uintptr_t bfaddr  = (uintptr_t)(binnedV + (size_t)nbV * CAPV);
    uint4*    Bfrag   = (uint4*)((bfaddr + 15) & ~(uintptr_t)15);  // 2048 uint4

    // zero copies + relative cursors in one memset
    hipMemsetAsync(copies, 0, (64 * 256 + (size_t)nbE + nbV) * sizeof(int), stream);

    const int nbin = (nnz + BIN_TILE - 1) / BIN_TILE;   // 391
    const int ncvt = 256;
    prep<<<nbin + ncvt + 4, 512, 0, stream>>>(nidx, eidx, curE, curV, binnedE, binnedV,
                                              nnz, nbE, nbV, nbin, ncvt,
                                              (const float4*)x, (uint2*)xh, N * CC / 4,
                                              W, Bfrag);

    fill_all<<<nbE + nbV, 512, 0, stream>>>(curE, curV, binnedE, binnedV, hw,
                                            rowsE, rowsV, Dinv, E, N, nbE);

    gather_n2e<<<(E + 7) / 8, 256, 0, stream>>>(rowsE, binnedE, (const uint4*)xh,
                                                (uint4*)eraw, E);

    mm_mfma<<<(E + 63) / 64, 256, 0, stream>>>((const uint4*)eraw, Bfrag,
                                               (unsigned short*)efeat, E);

    // xh is dead after hop1 -> reuse as bf16 pre-BN output buffer
    gather_e2n_bn<<<(N + 7) / 8, 256, 0, stream>>>(rowsV, binnedV, (const uint4*)efeat,
                                                   Dinv, b, (uint4*)xh, copies, N);

    bn_silu<<<1024, 256, 0, stream>>>((const uint2*)xh, copies, gamma, beta, out, N);
}

// Round 15
// 213.845 us; speedup vs baseline: 1.0614x; 1.0614x over previous
//
#include <hip/hip_runtime.h>
#include <cstdint>
#include <cstddef>

#define CC 128
#define LOG_FINE 7
#define FINE 128
#define CAPE 6144     // capacity per edge bucket (mean 4092, std ~64)
#define CAPV 3072     // capacity per node bucket (mean 2046, std ~45)
#define BIN_TILE 8192 // pairs per bin block (512 threads x 16)

typedef __attribute__((ext_vector_type(8))) short bf16x8;
typedef __attribute__((ext_vector_type(4))) float f32x4;

__device__ __forceinline__ unsigned f2b(float f) {
    const unsigned u = __float_as_uint(f);
    return (u + 0x7fffu + ((u >> 16) & 1u)) >> 16;
}
__device__ __forceinline__ float b2f_lo(unsigned u) { return __uint_as_float(u << 16); }
__device__ __forceinline__ float b2f_hi(unsigned u) { return __uint_as_float(u & 0xffff0000u); }

// ---- prep: [0,nbin) bin pairs; [nbin,nbin+ncvt) f32->bf16 convert; last 4 blocks: W B-frags ----
__global__ __launch_bounds__(512) void prep(const int* __restrict__ nidx,
                                            const int* __restrict__ eidx,
                                            int* __restrict__ curE,
                                            int* __restrict__ curV,
                                            unsigned* __restrict__ binnedE,
                                            unsigned* __restrict__ binnedV,
                                            int nnz, int nbE, int nbV, int nbin, int ncvt,
                                            const float4* __restrict__ xin,
                                            uint2* __restrict__ xh, int n4,
                                            const float* __restrict__ W,
                                            uint4* __restrict__ Bfrag) {
    __shared__ int cntE[512], gposE[512];
    __shared__ int cntV[1024], gposV[1024];
    const int tid = threadIdx.x;
    if (blockIdx.x >= (unsigned)(nbin + ncvt)) {
        // -------- B-fragment path (4 blocks x 512 = 2048) --------
        const int idx = (blockIdx.x - nbin - ncvt) * 512 + tid;
        if (idx < 2048) {
            const int lane = idx & 63, t = idx >> 6;
            const int kk = t >> 3, nt = t & 7;
            const int k0 = kk * 32 + (lane >> 4) * 8;
            const int n = nt * 16 + (lane & 15);
            unsigned r[4];
#pragma unroll
            for (int p = 0; p < 4; ++p) {
                const float w0 = W[(size_t)(k0 + 2 * p) * CC + n];
                const float w1 = W[(size_t)(k0 + 2 * p + 1) * CC + n];
                r[p] = f2b(w0) | (f2b(w1) << 16);
            }
            Bfrag[idx] = make_uint4(r[0], r[1], r[2], r[3]);
        }
        return;
    }
    if (blockIdx.x >= (unsigned)nbin) {
        // -------- convert path --------
        const int bid = blockIdx.x - nbin;
        for (int i = bid * 512 + tid; i < n4; i += ncvt * 512) {
            const float4 v = xin[i];
            xh[i] = make_uint2(f2b(v.x) | (f2b(v.y) << 16), f2b(v.z) | (f2b(v.w) << 16));
        }
        return;
    }
    // -------- bin path --------
    for (int i = tid; i < nbE; i += 512) cntE[i] = 0;
    for (int i = tid; i < nbV; i += 512) cntV[i] = 0;
    __syncthreads();
    const int base = blockIdx.x * BIN_TILE;
    int pE[16], rE[16], pV[16], rV[16];
#pragma unroll
    for (int j = 0; j < 16; ++j) {
        const int i = base + tid + j * 512;
        if (i < nnz) {
            const int e = eidx[i], v = nidx[i];
            const int bE = e >> LOG_FINE, bV = v >> LOG_FINE;
            rE[j] = (bE << 16) | atomicAdd(&cntE[bE], 1);
            pE[j] = (v << LOG_FINE) | (e & (FINE - 1));
            rV[j] = (bV << 16) | atomicAdd(&cntV[bV], 1);
            pV[j] = (e << LOG_FINE) | (v & (FINE - 1));
        } else { rE[j] = -1; rV[j] = -1; }
    }
    __syncthreads();
    for (int i = tid; i < nbE; i += 512) {
        const int c = cntE[i];
        gposE[i] = (c > 0) ? atomicAdd(&curE[i], c) : 0;   // relative offset
    }
    for (int i = tid; i < nbV; i += 512) {
        const int c = cntV[i];
        gposV[i] = (c > 0) ? atomicAdd(&curV[i], c) : 0;
    }
    __syncthreads();
#pragma unroll
    for (int j = 0; j < 16; ++j) {
        if (rE[j] >= 0) {
            const int b = rE[j] >> 16;
            binnedE[(size_t)b * CAPE + gposE[b] + (rE[j] & 0xffff)] = (unsigned)pE[j];
        }
        if (rV[j] >= 0) {
            const int b = rV[j] >> 16;
            binnedV[(size_t)b * CAPV + gposV[b] + (rV[j] & 0xffff)] = (unsigned)pV[j];
        }
    }
}

// ---------------- E-side per-bucket counting-sort (in place) + row ranges ----------------
__global__ __launch_bounds__(512) void fill_fineE(const int* __restrict__ cur,
                                                  unsigned* __restrict__ binned,
                                                  int2* __restrict__ rows, int nrows) {
    __shared__ unsigned vals[CAPE];
    __shared__ int scnt[FINE], soff[FINE], sscan[FINE];
    const int tid = threadIdx.x;
    const int b = blockIdx.x;
    const int base = b * CAPE;
    const int cnt = cur[b];                 // relative cursor == count
    for (int i = tid; i < cnt; i += 512) vals[i] = binned[base + i];
    if (tid < FINE) scnt[tid] = 0;
    __syncthreads();
    for (int i = tid; i < cnt; i += 512) atomicAdd(&scnt[vals[i] & (FINE - 1)], 1);
    __syncthreads();
    if (tid < FINE) sscan[tid] = scnt[tid];
    __syncthreads();
#pragma unroll
    for (int d = 1; d < FINE; d <<= 1) {
        int t = 0;
        if (tid >= d && tid < FINE) t = sscan[tid - d];
        __syncthreads();
        if (tid < FINE) sscan[tid] += t;
        __syncthreads();
    }
    if (tid < FINE) {
        const int excl = sscan[tid] - scnt[tid];
        soff[tid] = excl;
        const int row = (b << LOG_FINE) + tid;
        if (row < nrows) rows[row] = make_int2(base + excl, base + excl + scnt[tid]);
    }
    __syncthreads();
    for (int i = tid; i < cnt; i += 512) {
        const unsigned p = vals[i];
        const int slot = (int)(p & (FINE - 1));
        const int pos = base + atomicAdd(&soff[slot], 1);
        binned[pos] = p >> LOG_FINE;
    }
}

// ---- fused: blocks [0,ngather) = hop1 gather (LONG POLE FIRST); [ngather,..) = fillV (+Dinv) ----
__global__ __launch_bounds__(512) void fillV_gather(const int* __restrict__ curV,
                                                    unsigned* __restrict__ binnedV,
                                                    const float* __restrict__ hw,
                                                    int2* __restrict__ rowsV,
                                                    float* __restrict__ Dinv,
                                                    int N, int ngather,
                                                    const int2* __restrict__ rowsE,
                                                    const unsigned* __restrict__ binnedE,
                                                    const uint4* __restrict__ xh4,
                                                    uint4* __restrict__ eraw4, int E) {
    __shared__ unsigned vals[CAPV];
    __shared__ int scnt[FINE], soff[FINE], sscan[FINE];
    __shared__ float sd[FINE];
    const int tid = threadIdx.x;
    if (blockIdx.x >= (unsigned)ngather) {
        // -------- fillV path (scheduled after the gather long-pole) --------
        const int b = blockIdx.x - ngather;
        const int base = b * CAPV;
        const int cnt = curV[b];
        for (int i = tid; i < cnt; i += 512) vals[i] = binnedV[base + i];
        if (tid < FINE) { scnt[tid] = 0; sd[tid] = 0.f; }
        __syncthreads();
        for (int i = tid; i < cnt; i += 512) atomicAdd(&scnt[vals[i] & (FINE - 1)], 1);
        __syncthreads();
        if (tid < FINE) sscan[tid] = scnt[tid];
        __syncthreads();
#pragma unroll
        for (int d = 1; d < FINE; d <<= 1) {
            int t = 0;
            if (tid >= d && tid < FINE) t = sscan[tid - d];
            __syncthreads();
            if (tid < FINE) sscan[tid] += t;
            __syncthreads();
        }
        if (tid < FINE) {
            const int excl = sscan[tid] - scnt[tid];
            soff[tid] = excl;
            const int row = (b << LOG_FINE) + tid;
            if (row < N) rowsV[row] = make_int2(base + excl, base + excl + scnt[tid]);
        }
        __syncthreads();
        for (int i = tid; i < cnt; i += 512) {
            const unsigned p = vals[i];
            const int slot = (int)(p & (FINE - 1));
            const int e = (int)(p >> LOG_FINE);
            const int pos = base + atomicAdd(&soff[slot], 1);
            binnedV[pos] = (unsigned)e;
            atomicAdd(&sd[slot], hw[e]);
        }
        __syncthreads();
        if (tid < FINE) {
            const int row = (b << LOG_FINE) + tid;
            if (row < N) {
                const float d = sd[tid];
                Dinv[row] = (d > 0.f) ? 1.f / d : 0.f;
            }
        }
        return;
    }
    // -------- hop1 gather path: 16 subwarps, 1 edge each --------
    const int sub = tid >> 5;
    const int half = (tid >> 4) & 1;
    const int q = tid & 15;
    const int e = blockIdx.x * 16 + sub;
    if (e >= E) return;
    const int2 st = rowsE[e];
    const int s = st.x, t = st.y;
    float a[8];
#pragma unroll
    for (int k = 0; k < 8; ++k) a[k] = 0.f;
    int j = s;
    for (; j + 7 < t; j += 8) {
        const int v0 = (int)binnedE[j + 0 + half];
        const int v1 = (int)binnedE[j + 2 + half];
        const int v2 = (int)binnedE[j + 4 + half];
        const int v3 = (int)binnedE[j + 6 + half];
        const uint4 u0 = xh4[(size_t)v0 * 16 + q];
        const uint4 u1 = xh4[(size_t)v1 * 16 + q];
        const uint4 u2 = xh4[(size_t)v2 * 16 + q];
        const uint4 u3 = xh4[(size_t)v3 * 16 + q];
        a[0] += b2f_lo(u0.x) + b2f_lo(u1.x) + b2f_lo(u2.x) + b2f_lo(u3.x);
        a[1] += b2f_hi(u0.x) + b2f_hi(u1.x) + b2f_hi(u2.x) + b2f_hi(u3.x);
        a[2] += b2f_lo(u0.y) + b2f_lo(u1.y) + b2f_lo(u2.y) + b2f_lo(u3.y);
        a[3] += b2f_hi(u0.y) + b2f_hi(u1.y) + b2f_hi(u2.y) + b2f_hi(u3.y);
        a[4] += b2f_lo(u0.z) + b2f_lo(u1.z) + b2f_lo(u2.z) + b2f_lo(u3.z);
        a[5] += b2f_hi(u0.z) + b2f_hi(u1.z) + b2f_hi(u2.z) + b2f_hi(u3.z);
        a[6] += b2f_lo(u0.w) + b2f_lo(u1.w) + b2f_lo(u2.w) + b2f_lo(u3.w);
        a[7] += b2f_hi(u0.w) + b2f_hi(u1.w) + b2f_hi(u2.w) + b2f_hi(u3.w);
    }
    for (; j + 1 < t; j += 2) {
        const int v0 = (int)binnedE[j + half];
        const uint4 u = xh4[(size_t)v0 * 16 + q];
        a[0] += b2f_lo(u.x); a[1] += b2f_hi(u.x);
        a[2] += b2f_lo(u.y); a[3] += b2f_hi(u.y);
        a[4] += b2f_lo(u.z); a[5] += b2f_hi(u.z);
        a[6] += b2f_lo(u.w); a[7] += b2f_hi(u.w);
    }
    if (j < t && half == 0) {
        const uint4 u = xh4[(size_t)binnedE[j] * 16 + q];
        a[0] += b2f_lo(u.x); a[1] += b2f_hi(u.x);
        a[2] += b2f_lo(u.y); a[3] += b2f_hi(u.y);
        a[4] += b2f_lo(u.z); a[5] += b2f_hi(u.z);
        a[6] += b2f_lo(u.w); a[7] += b2f_hi(u.w);
    }
#pragma unroll
    for (int k = 0; k < 8; ++k) a[k] += __shfl_xor(a[k], 16);
    if (half == 0) {
        const float binv = (t > s) ? 1.f / (float)(t - s) : 0.f;
#pragma unroll
        for (int k = 0; k < 8; ++k) a[k] *= binv;
        uint4 o;
        o.x = f2b(a[0]) | (f2b(a[1]) << 16);
        o.y = f2b(a[2]) | (f2b(a[3]) << 16);
        o.z = f2b(a[4]) | (f2b(a[5]) << 16);
        o.w = f2b(a[6]) | (f2b(a[7]) << 16);
        eraw4[(size_t)e * 16 + q] = o;
    }
}

// ---- mm via MFMA: efeat[M,128](bf16) = eraw[M,128](bf16) @ W (B-frags precomputed) ----
__global__ __launch_bounds__(256) void mm_mfma(const uint4* __restrict__ A4,
                                               const uint4* __restrict__ Bfrag,
                                               unsigned short* __restrict__ Out, int M) {
    const int lane = threadIdx.x & 63;
    const int wave = threadIdx.x >> 6;
    const int row0 = blockIdx.x * 64 + wave * 16;
    const int g = lane >> 4;
    const int c = lane & 15;
    const int arow = row0 + c;
    uint4 a[4];
#pragma unroll
    for (int kk = 0; kk < 4; ++kk) {
        a[kk] = (arow < M) ? A4[(size_t)arow * 16 + kk * 4 + g]
                           : make_uint4(0u, 0u, 0u, 0u);
    }
    f32x4 acc[8];
#pragma unroll
    for (int nt = 0; nt < 8; ++nt) acc[nt] = (f32x4){0.f, 0.f, 0.f, 0.f};
#pragma unroll
    for (int nt = 0; nt < 8; ++nt) {
#pragma unroll
        for (int kk = 0; kk < 4; ++kk) {
            const uint4 bv = Bfrag[(kk * 8 + nt) * 64 + lane];
            acc[nt] = __builtin_amdgcn_mfma_f32_16x16x32_bf16(
                *(const bf16x8*)&a[kk], *(const bf16x8*)&bv, acc[nt], 0, 0, 0);
        }
    }
#pragma unroll
    for (int nt = 0; nt < 8; ++nt) {
#pragma unroll
        for (int r = 0; r < 4; ++r) {
            const int row = row0 + g * 4 + r;
            if (row < M) Out[(size_t)row * CC + nt * 16 + c] = (unsigned short)f2b(acc[nt][r]);
        }
    }
}

// ---- hop2 + BN stats: oh[v](bf16) = Dinv*sum efeat + b; both halves write owned LDS slots ----
__global__ __launch_bounds__(256) void gather_e2n_bn(const int2* __restrict__ rows,
                                                     const unsigned* __restrict__ lst,
                                                     const uint4* __restrict__ ef4,
                                                     const float* __restrict__ Dinv,
                                                     const float* __restrict__ b,
                                                     uint4* __restrict__ oh,
                                                     float* __restrict__ copies, int N) {
    // row stride 268: sums at col 8q..8q+7, squares at col 132+8q.. (disjoint bank phases)
    __shared__ float bl[8][268];
    const int tid = threadIdx.x;
    const int sub = tid >> 5;
    const int half = (tid >> 4) & 1;
    const int q = tid & 15;
    const int v = blockIdx.x * 8 + sub;
    if (v < N) {
        const int2 st = rows[v];
        const int s = st.x, t = st.y;
        float a[8];
#pragma unroll
        for (int k = 0; k < 8; ++k) a[k] = 0.f;
        int j = s;
        for (; j + 7 < t; j += 8) {
            const int e0 = (int)lst[j + 0 + half];
            const int e1 = (int)lst[j + 2 + half];
            const int e2 = (int)lst[j + 4 + half];
            const int e3 = (int)lst[j + 6 + half];
            const uint4 u0 = ef4[(size_t)e0 * 16 + q];
            const uint4 u1 = ef4[(size_t)e1 * 16 + q];
            const uint4 u2 = ef4[(size_t)e2 * 16 + q];
            const uint4 u3 = ef4[(size_t)e3 * 16 + q];
            a[0] += b2f_lo(u0.x) + b2f_lo(u1.x) + b2f_lo(u2.x) + b2f_lo(u3.x);
            a[1] += b2f_hi(u0.x) + b2f_hi(u1.x) + b2f_hi(u2.x) + b2f_hi(u3.x);
            a[2] += b2f_lo(u0.y) + b2f_lo(u1.y) + b2f_lo(u2.y) + b2f_lo(u3.y);
            a[3] += b2f_hi(u0.y) + b2f_hi(u1.y) + b2f_hi(u2.y) + b2f_hi(u3.y);
            a[4] += b2f_lo(u0.z) + b2f_lo(u1.z) + b2f_lo(u2.z) + b2f_lo(u3.z);
            a[5] += b2f_hi(u0.z) + b2f_hi(u1.z) + b2f_hi(u2.z) + b2f_hi(u3.z);
            a[6] += b2f_lo(u0.w) + b2f_lo(u1.w) + b2f_lo(u2.w) + b2f_lo(u3.w);
            a[7] += b2f_hi(u0.w) + b2f_hi(u1.w) + b2f_hi(u2.w) + b2f_hi(u3.w);
        }
        for (; j + 1 < t; j += 2) {
            const int e0 = (int)lst[j + half];
            const uint4 u = ef4[(size_t)e0 * 16 + q];
            a[0] += b2f_lo(u.x); a[1] += b2f_hi(u.x);
            a[2] += b2f_lo(u.y); a[3] += b2f_hi(u.y);
            a[4] += b2f_lo(u.z); a[5] += b2f_hi(u.z);
            a[6] += b2f_lo(u.w); a[7] += b2f_hi(u.w);
        }
        if (j < t && half == 0) {
            const uint4 u = ef4[(size_t)lst[j] * 16 + q];
            a[0] += b2f_lo(u.x); a[1] += b2f_hi(u.x);
            a[2] += b2f_lo(u.y); a[3] += b2f_hi(u.y);
            a[4] += b2f_lo(u.z); a[5] += b2f_hi(u.z);
            a[6] += b2f_lo(u.w); a[7] += b2f_hi(u.w);
        }
#pragma unroll
        for (int k = 0; k < 8; ++k) a[k] += __shfl_xor(a[k], 16);
        // both halves now hold the full sums: compute o on both
        const float dinv = Dinv[v];
        const float4 b0 = *(const float4*)&b[8 * q];
        const float4 b1 = *(const float4*)&b[8 * q + 4];
        float o[8];
        o[0] = a[0] * dinv + b0.x; o[1] = a[1] * dinv + b0.y;
        o[2] = a[2] * dinv + b0.z; o[3] = a[3] * dinv + b0.w;
        o[4] = a[4] * dinv + b1.x; o[5] = a[5] * dinv + b1.y;
        o[6] = a[6] * dinv + b1.z; o[7] = a[7] * dinv + b1.w;
        if (half == 0) {
            uint4 ov;
            ov.x = f2b(o[0]) | (f2b(o[1]) << 16);
            ov.y = f2b(o[2]) | (f2b(o[3]) << 16);
            ov.z = f2b(o[4]) | (f2b(o[5]) << 16);
            ov.w = f2b(o[6]) | (f2b(o[7]) << 16);
            oh[(size_t)v * 16 + q] = ov;
            *(float4*)&bl[sub][8 * q]     = make_float4(o[0], o[1], o[2], o[3]);
            *(float4*)&bl[sub][8 * q + 4] = make_float4(o[4], o[5], o[6], o[7]);
        } else {
            *(float4*)&bl[sub][132 + 8 * q] = make_float4(o[0] * o[0], o[1] * o[1],
                                                          o[2] * o[2], o[3] * o[3]);
            *(float4*)&bl[sub][136 + 8 * q] = make_float4(o[4] * o[4], o[5] * o[5],
                                                          o[6] * o[6], o[7] * o[7]);
        }
    } else {
        const float4 z4 = make_float4(0.f, 0.f, 0.f, 0.f);
        if (half == 0) {
            *(float4*)&bl[sub][8 * q] = z4;
            *(float4*)&bl[sub][8 * q + 4] = z4;
        } else {
            *(float4*)&bl[sub][132 + 8 * q] = z4;
            *(float4*)&bl[sub][136 + 8 * q] = z4;
        }
    }
    __syncthreads();
    const int col = (tid < 128) ? tid : (tid + 4);   // squares live at +4 rotation
    float s = 0.f;
#pragma unroll
    for (int i = 0; i < 8; ++i) s += bl[i][col];
    atomicAdd(&copies[(blockIdx.x & 63) * 256 + tid], s);
}

// ---- BN normalize + SiLU: reduce 64 sum-copies, read bf16 pre-BN, write f32 ----
__global__ __launch_bounds__(256) void bn_silu(const uint2* __restrict__ oh2,
                                               const float* __restrict__ copies,
                                               const float* __restrict__ gamma,
                                               const float* __restrict__ beta,
                                               float* __restrict__ out, int N) {
    __shared__ float sl[256];
    const int tid = threadIdx.x;
    float s = 0.f;
#pragma unroll 8
    for (int i = 0; i < 64; ++i) s += copies[i * 256 + tid];
    sl[tid] = s;
    __syncthreads();
    const int sub = tid >> 5;
    const int lane = tid & 31;
    const int c4 = lane * 4;
    const float invN = 1.0f / (float)N;
    float g[4], bb[4];
#pragma unroll
    for (int k = 0; k < 4; ++k) {
        const float mean = sl[c4 + k] * invN;
        float var = sl[128 + c4 + k] * invN - mean * mean;
        var = fmaxf(var, 0.f);
        const float istd = rsqrtf(var + 1e-5f);
        g[k] = gamma[c4 + k] * istd;
        bb[k] = beta[c4 + k] - mean * g[k];
    }
    for (int v = blockIdx.x * 8 + sub; v < N; v += gridDim.x * 8) {
        const uint2 u = oh2[(size_t)v * 32 + lane];
        float y[4];
        y[0] = b2f_lo(u.x); y[1] = b2f_hi(u.x);
        y[2] = b2f_lo(u.y); y[3] = b2f_hi(u.y);
        float4 o;
#pragma unroll
        for (int k = 0; k < 4; ++k) {
            const float z = y[k] * g[k] + bb[k];
            (&o.x)[k] = z / (1.f + __expf(-z));
        }
        *(float4*)&out[(size_t)v * CC + c4] = o;
    }
}

extern "C" void kernel_launch(void* const* d_in, const int* in_sizes, int n_in,
                              void* d_out, int out_size, void* d_ws, size_t ws_size,
                              hipStream_t stream) {
    const float* x     = (const float*)d_in[0];
    const int*   hidx  = (const int*)d_in[1];
    const float* hw    = (const float*)d_in[2];
    const float* W     = (const float*)d_in[3];
    const float* b     = (const float*)d_in[4];
    const float* gamma = (const float*)d_in[5];
    const float* beta  = (const float*)d_in[6];

    const int N   = in_sizes[0] / CC;   // 100000
    const int nnz = in_sizes[1] / 2;    // 1600000
    const int E   = in_sizes[2];        // 50000

    const int* nidx = hidx;
    const int* eidx = hidx + nnz;

    float* out = (float*)d_out;

    const int nbE = (E + FINE - 1) / FINE;   // 391
    const int nbV = (N + FINE - 1) / FINE;   // 782

    unsigned* ws      = (unsigned*)d_ws;
    unsigned* xh      = ws;                              // N*64 uints (bf16 x; reused as oh)
    unsigned* eraw    = xh + (size_t)N * 64;             // E*64
    unsigned* efeat   = eraw + (size_t)E * 64;           // E*64
    int2*     rowsE   = (int2*)(efeat + (size_t)E * 64); // E int2
    int2*     rowsV   = rowsE + E;                       // N int2
    float*    Dinv    = (float*)(rowsV + N);             // N floats
    float*    copies  = Dinv + N;                        // 64*256 floats
    int*      curE    = (int*)(copies + 64 * 256);       // nbE (relative)
    int*      curV    = curE + nbE;                      // nbV (relative)
    unsigned* binnedE = (unsigned*)(curV + nbV);         // nbE*CAPE
    unsigned* binnedV = binnedE + (size_t)nbE * CAPE;    // nbV*CAPV
    uintptr_t bfaddr  = (uintptr_t)(binnedV + (size_t)nbV * CAPV);
    uint4*    Bfrag   = (uint4*)((bfaddr + 15) & ~(uintptr_t)15);  // 2048 uint4

    // zero copies + relative cursors in one memset
    hipMemsetAsync(copies, 0, (64 * 256 + (size_t)nbE + nbV) * sizeof(int), stream);

    const int nbin = (nnz + BIN_TILE - 1) / BIN_TILE;   // 196
    const int ncvt = 256;
    prep<<<nbin + ncvt + 4, 512, 0, stream>>>(nidx, eidx, curE, curV, binnedE, binnedV,
                                              nnz, nbE, nbV, nbin, ncvt,
                                              (const float4*)x, (uint2*)xh, N * CC / 4,
                                              W, Bfrag);

    fill_fineE<<<nbE, 512, 0, stream>>>(curE, binnedE, rowsE, E);

    const int ngather = (E + 15) / 16;   // 3125 gather blocks first, then nbV fillV blocks
    fillV_gather<<<ngather + nbV, 512, 0, stream>>>(
        curV, binnedV, hw, rowsV, Dinv, N, ngather,
        rowsE, binnedE, (const uint4*)xh, (uint4*)eraw, E);

    mm_mfma<<<(E + 63) / 64, 256, 0, stream>>>((const uint4*)eraw, Bfrag,
                                               (unsigned short*)efeat, E);

    // xh is dead after hop1 -> reuse as bf16 pre-BN output buffer
    gather_e2n_bn<<<(N + 7) / 8, 256, 0, stream>>>(rowsV, binnedV, (const uint4*)efeat,
                                                   Dinv, b, (uint4*)xh, copies, N);

    bn_silu<<<1024, 256, 0, stream>>>((const uint2*)xh, copies, gamma, beta, out, N);
}

// Round 16
// 213.836 us; speedup vs baseline: 1.0615x; 1.0000x over previous
//
#include <hip/hip_runtime.h>
#include <cstdint>
#include <cstddef>

#define CC 128
#define LOG_FINE 7
#define FINE 128
#define CAPE 6144     // capacity per edge bucket (mean 4092, std ~64)
#define CAPV 3072     // capacity per node bucket (mean 2046, std ~45)
#define BIN_TILE 8192 // pairs per bin block (512 threads x 16)

typedef __attribute__((ext_vector_type(8))) short bf16x8;
typedef __attribute__((ext_vector_type(4))) float f32x4;

__device__ __forceinline__ unsigned f2b(float f) {
    const unsigned u = __float_as_uint(f);
    return (u + 0x7fffu + ((u >> 16) & 1u)) >> 16;
}
__device__ __forceinline__ float b2f_lo(unsigned u) { return __uint_as_float(u << 16); }
__device__ __forceinline__ float b2f_hi(unsigned u) { return __uint_as_float(u & 0xffff0000u); }

// ---- prep: [0,nbin) bin pairs; [nbin,nbin+ncvt) f32->bf16 convert; last 4 blocks: W B-frags ----
__global__ __launch_bounds__(512) void prep(const int* __restrict__ nidx,
                                            const int* __restrict__ eidx,
                                            int* __restrict__ curE,
                                            int* __restrict__ curV,
                                            unsigned* __restrict__ binnedE,
                                            unsigned* __restrict__ binnedV,
                                            int nnz, int nbE, int nbV, int nbin, int ncvt,
                                            const float4* __restrict__ xin,
                                            uint2* __restrict__ xh, int n4,
                                            const float* __restrict__ W,
                                            uint4* __restrict__ Bfrag) {
    __shared__ int cntE[512], gposE[512];
    __shared__ int cntV[1024], gposV[1024];
    const int tid = threadIdx.x;
    if (blockIdx.x >= (unsigned)(nbin + ncvt)) {
        // -------- B-fragment path (4 blocks x 512 = 2048) --------
        const int idx = (blockIdx.x - nbin - ncvt) * 512 + tid;
        if (idx < 2048) {
            const int lane = idx & 63, t = idx >> 6;
            const int kk = t >> 3, nt = t & 7;
            const int k0 = kk * 32 + (lane >> 4) * 8;
            const int n = nt * 16 + (lane & 15);
            unsigned r[4];
#pragma unroll
            for (int p = 0; p < 4; ++p) {
                const float w0 = W[(size_t)(k0 + 2 * p) * CC + n];
                const float w1 = W[(size_t)(k0 + 2 * p + 1) * CC + n];
                r[p] = f2b(w0) | (f2b(w1) << 16);
            }
            Bfrag[idx] = make_uint4(r[0], r[1], r[2], r[3]);
        }
        return;
    }
    if (blockIdx.x >= (unsigned)nbin) {
        // -------- convert path --------
        const int bid = blockIdx.x - nbin;
        for (int i = bid * 512 + tid; i < n4; i += ncvt * 512) {
            const float4 v = xin[i];
            xh[i] = make_uint2(f2b(v.x) | (f2b(v.y) << 16), f2b(v.z) | (f2b(v.w) << 16));
        }
        return;
    }
    // -------- bin path --------
    for (int i = tid; i < nbE; i += 512) cntE[i] = 0;
    for (int i = tid; i < nbV; i += 512) cntV[i] = 0;
    __syncthreads();
    const int base = blockIdx.x * BIN_TILE;
    int pE[16], rE[16], pV[16], rV[16];
#pragma unroll
    for (int j = 0; j < 16; ++j) {
        const int i = base + tid + j * 512;
        if (i < nnz) {
            const int e = eidx[i], v = nidx[i];
            const int bE = e >> LOG_FINE, bV = v >> LOG_FINE;
            rE[j] = (bE << 16) | atomicAdd(&cntE[bE], 1);
            pE[j] = (v << LOG_FINE) | (e & (FINE - 1));
            rV[j] = (bV << 16) | atomicAdd(&cntV[bV], 1);
            pV[j] = (e << LOG_FINE) | (v & (FINE - 1));
        } else { rE[j] = -1; rV[j] = -1; }
    }
    __syncthreads();
    for (int i = tid; i < nbE; i += 512) {
        const int c = cntE[i];
        gposE[i] = (c > 0) ? atomicAdd(&curE[i], c) : 0;   // relative offset
    }
    for (int i = tid; i < nbV; i += 512) {
        const int c = cntV[i];
        gposV[i] = (c > 0) ? atomicAdd(&curV[i], c) : 0;
    }
    __syncthreads();
#pragma unroll
    for (int j = 0; j < 16; ++j) {
        if (rE[j] >= 0) {
            const int b = rE[j] >> 16;
            binnedE[(size_t)b * CAPE + gposE[b] + (rE[j] & 0xffff)] = (unsigned)pE[j];
        }
        if (rV[j] >= 0) {
            const int b = rV[j] >> 16;
            binnedV[(size_t)b * CAPV + gposV[b] + (rV[j] & 0xffff)] = (unsigned)pV[j];
        }
    }
}

// ---- merged per-bucket counting-sort: blocks [0,nbE)=E side; [nbE,nbE+nbV)=V side (+Dinv) ----
__global__ __launch_bounds__(512) void fill_all(const int* __restrict__ curE,
                                                const int* __restrict__ curV,
                                                unsigned* __restrict__ binnedE,
                                                unsigned* __restrict__ binnedV,
                                                const float* __restrict__ hw,
                                                int2* __restrict__ rowsE,
                                                int2* __restrict__ rowsV,
                                                float* __restrict__ Dinv,
                                                int E, int N, int nbE) {
    __shared__ unsigned vals[CAPE];
    __shared__ int scnt[FINE], soff[FINE], sscan[FINE];
    __shared__ float sd[FINE];
    const int tid = threadIdx.x;
    const bool isE = (blockIdx.x < (unsigned)nbE);
    const int b = isE ? blockIdx.x : blockIdx.x - nbE;
    const int cap = isE ? CAPE : CAPV;
    const int base = b * cap;
    const int cnt = isE ? curE[b] : curV[b];   // relative cursor == count
    unsigned* binned = isE ? binnedE : binnedV;
    int2* rows = isE ? rowsE : rowsV;
    const int nrows = isE ? E : N;
    for (int i = tid; i < cnt; i += 512) vals[i] = binned[base + i];
    if (tid < FINE) { scnt[tid] = 0; sd[tid] = 0.f; }
    __syncthreads();
    for (int i = tid; i < cnt; i += 512) atomicAdd(&scnt[vals[i] & (FINE - 1)], 1);
    __syncthreads();
    if (tid < FINE) sscan[tid] = scnt[tid];
    __syncthreads();
#pragma unroll
    for (int d = 1; d < FINE; d <<= 1) {
        int t = 0;
        if (tid >= d && tid < FINE) t = sscan[tid - d];
        __syncthreads();
        if (tid < FINE) sscan[tid] += t;
        __syncthreads();
    }
    if (tid < FINE) {
        const int excl = sscan[tid] - scnt[tid];
        soff[tid] = excl;
        const int row = (b << LOG_FINE) + tid;
        if (row < nrows) rows[row] = make_int2(base + excl, base + excl + scnt[tid]);
    }
    __syncthreads();
    if (isE) {
        for (int i = tid; i < cnt; i += 512) {
            const unsigned p = vals[i];
            const int slot = (int)(p & (FINE - 1));
            const int pos = base + atomicAdd(&soff[slot], 1);
            binned[pos] = p >> LOG_FINE;
        }
    } else {
        for (int i = tid; i < cnt; i += 512) {
            const unsigned p = vals[i];
            const int slot = (int)(p & (FINE - 1));
            const int e = (int)(p >> LOG_FINE);
            const int pos = base + atomicAdd(&soff[slot], 1);
            binned[pos] = (unsigned)e;
            atomicAdd(&sd[slot], hw[e]);
        }
        __syncthreads();
        if (tid < FINE) {
            const int row = (b << LOG_FINE) + tid;
            if (row < N) {
                const float d = sd[tid];
                Dinv[row] = (d > 0.f) ? 1.f / d : 0.f;
            }
        }
    }
}

// ---- hop1: eraw[e,:] = (1/|e|) * sum_{v in e} xh[v,:]; 16 lanes/row, uint4, one-shot ----
__global__ __launch_bounds__(256) void gather_n2e(const int2* __restrict__ rows,
                                                  const unsigned* __restrict__ lst,
                                                  const uint4* __restrict__ xh4,
                                                  uint4* __restrict__ eraw4, int E) {
    const int sub = threadIdx.x >> 5;
    const int half = (threadIdx.x >> 4) & 1;
    const int q = threadIdx.x & 15;
    const int e = blockIdx.x * 8 + sub;
    if (e >= E) return;
    const int2 st = rows[e];
    const int s = st.x, t = st.y;
    float a[8];
#pragma unroll
    for (int k = 0; k < 8; ++k) a[k] = 0.f;
    int j = s;
    for (; j + 7 < t; j += 8) {
        const int v0 = (int)lst[j + 0 + half];
        const int v1 = (int)lst[j + 2 + half];
        const int v2 = (int)lst[j + 4 + half];
        const int v3 = (int)lst[j + 6 + half];
        const uint4 u0 = xh4[(size_t)v0 * 16 + q];
        const uint4 u1 = xh4[(size_t)v1 * 16 + q];
        const uint4 u2 = xh4[(size_t)v2 * 16 + q];
        const uint4 u3 = xh4[(size_t)v3 * 16 + q];
        a[0] += b2f_lo(u0.x) + b2f_lo(u1.x) + b2f_lo(u2.x) + b2f_lo(u3.x);
        a[1] += b2f_hi(u0.x) + b2f_hi(u1.x) + b2f_hi(u2.x) + b2f_hi(u3.x);
        a[2] += b2f_lo(u0.y) + b2f_lo(u1.y) + b2f_lo(u2.y) + b2f_lo(u3.y);
        a[3] += b2f_hi(u0.y) + b2f_hi(u1.y) + b2f_hi(u2.y) + b2f_hi(u3.y);
        a[4] += b2f_lo(u0.z) + b2f_lo(u1.z) + b2f_lo(u2.z) + b2f_lo(u3.z);
        a[5] += b2f_hi(u0.z) + b2f_hi(u1.z) + b2f_hi(u2.z) + b2f_hi(u3.z);
        a[6] += b2f_lo(u0.w) + b2f_lo(u1.w) + b2f_lo(u2.w) + b2f_lo(u3.w);
        a[7] += b2f_hi(u0.w) + b2f_hi(u1.w) + b2f_hi(u2.w) + b2f_hi(u3.w);
    }
    for (; j + 1 < t; j += 2) {
        const int v0 = (int)lst[j + half];
        const uint4 u = xh4[(size_t)v0 * 16 + q];
        a[0] += b2f_lo(u.x); a[1] += b2f_hi(u.x);
        a[2] += b2f_lo(u.y); a[3] += b2f_hi(u.y);
        a[4] += b2f_lo(u.z); a[5] += b2f_hi(u.z);
        a[6] += b2f_lo(u.w); a[7] += b2f_hi(u.w);
    }
    if (j < t && half == 0) {
        const uint4 u = xh4[(size_t)lst[j] * 16 + q];
        a[0] += b2f_lo(u.x); a[1] += b2f_hi(u.x);
        a[2] += b2f_lo(u.y); a[3] += b2f_hi(u.y);
        a[4] += b2f_lo(u.z); a[5] += b2f_hi(u.z);
        a[6] += b2f_lo(u.w); a[7] += b2f_hi(u.w);
    }
#pragma unroll
    for (int k = 0; k < 8; ++k) a[k] += __shfl_xor(a[k], 16);
    if (half == 0) {
        const float binv = (t > s) ? 1.f / (float)(t - s) : 0.f;
#pragma unroll
        for (int k = 0; k < 8; ++k) a[k] *= binv;
        uint4 o;
        o.x = f2b(a[0]) | (f2b(a[1]) << 16);
        o.y = f2b(a[2]) | (f2b(a[3]) << 16);
        o.z = f2b(a[4]) | (f2b(a[5]) << 16);
        o.w = f2b(a[6]) | (f2b(a[7]) << 16);
        eraw4[(size_t)e * 16 + q] = o;
    }
}

// ---- mm via MFMA: efeat[M,128](bf16) = eraw[M,128](bf16) @ W (B-frags precomputed) ----
__global__ __launch_bounds__(256) void mm_mfma(const uint4* __restrict__ A4,
                                               const uint4* __restrict__ Bfrag,
                                               unsigned short* __restrict__ Out, int M) {
    const int lane = threadIdx.x & 63;
    const int wave = threadIdx.x >> 6;
    const int row0 = blockIdx.x * 64 + wave * 16;
    const int g = lane >> 4;
    const int c = lane & 15;
    const int arow = row0 + c;
    uint4 a[4];
#pragma unroll
    for (int kk = 0; kk < 4; ++kk) {
        a[kk] = (arow < M) ? A4[(size_t)arow * 16 + kk * 4 + g]
                           : make_uint4(0u, 0u, 0u, 0u);
    }
    f32x4 acc[8];
#pragma unroll
    for (int nt = 0; nt < 8; ++nt) acc[nt] = (f32x4){0.f, 0.f, 0.f, 0.f};
#pragma unroll
    for (int nt = 0; nt < 8; ++nt) {
#pragma unroll
        for (int kk = 0; kk < 4; ++kk) {
            const uint4 bv = Bfrag[(kk * 8 + nt) * 64 + lane];
            acc[nt] = __builtin_amdgcn_mfma_f32_16x16x32_bf16(
                *(const bf16x8*)&a[kk], *(const bf16x8*)&bv, acc[nt], 0, 0, 0);
        }
    }
#pragma unroll
    for (int nt = 0; nt < 8; ++nt) {
#pragma unroll
        for (int r = 0; r < 4; ++r) {
            const int row = row0 + g * 4 + r;
            if (row < M) Out[(size_t)row * CC + nt * 16 + c] = (unsigned short)f2b(acc[nt][r]);
        }
    }
}

// ---- hop2 + BN stats: oh[v](bf16) = Dinv*sum efeat + b; both halves write owned LDS slots ----
__global__ __launch_bounds__(256) void gather_e2n_bn(const int2* __restrict__ rows,
                                                     const unsigned* __restrict__ lst,
                                                     const uint4* __restrict__ ef4,
                                                     const float* __restrict__ Dinv,
                                                     const float* __restrict__ b,
                                                     uint4* __restrict__ oh,
                                                     float* __restrict__ copies, int N) {
    // row stride 268: sums at col 8q..8q+7, squares at col 132+8q.. (disjoint bank phases)
    __shared__ float bl[8][268];
    const int tid = threadIdx.x;
    const int sub = tid >> 5;
    const int half = (tid >> 4) & 1;
    const int q = tid & 15;
    const int v = blockIdx.x * 8 + sub;
    if (v < N) {
        const int2 st = rows[v];
        const int s = st.x, t = st.y;
        float a[8];
#pragma unroll
        for (int k = 0; k < 8; ++k) a[k] = 0.f;
        int j = s;
        for (; j + 7 < t; j += 8) {
            const int e0 = (int)lst[j + 0 + half];
            const int e1 = (int)lst[j + 2 + half];
            const int e2 = (int)lst[j + 4 + half];
            const int e3 = (int)lst[j + 6 + half];
            const uint4 u0 = ef4[(size_t)e0 * 16 + q];
            const uint4 u1 = ef4[(size_t)e1 * 16 + q];
            const uint4 u2 = ef4[(size_t)e2 * 16 + q];
            const uint4 u3 = ef4[(size_t)e3 * 16 + q];
            a[0] += b2f_lo(u0.x) + b2f_lo(u1.x) + b2f_lo(u2.x) + b2f_lo(u3.x);
            a[1] += b2f_hi(u0.x) + b2f_hi(u1.x) + b2f_hi(u2.x) + b2f_hi(u3.x);
            a[2] += b2f_lo(u0.y) + b2f_lo(u1.y) + b2f_lo(u2.y) + b2f_lo(u3.y);
            a[3] += b2f_hi(u0.y) + b2f_hi(u1.y) + b2f_hi(u2.y) + b2f_hi(u3.y);
            a[4] += b2f_lo(u0.z) + b2f_lo(u1.z) + b2f_lo(u2.z) + b2f_lo(u3.z);
            a[5] += b2f_hi(u0.z) + b2f_hi(u1.z) + b2f_hi(u2.z) + b2f_hi(u3.z);
            a[6] += b2f_lo(u0.w) + b2f_lo(u1.w) + b2f_lo(u2.w) + b2f_lo(u3.w);
            a[7] += b2f_hi(u0.w) + b2f_hi(u1.w) + b2f_hi(u2.w) + b2f_hi(u3.w);
        }
        for (; j + 1 < t; j += 2) {
            const int e0 = (int)lst[j + half];
            const uint4 u = ef4[(size_t)e0 * 16 + q];
            a[0] += b2f_lo(u.x); a[1] += b2f_hi(u.x);
            a[2] += b2f_lo(u.y); a[3] += b2f_hi(u.y);
            a[4] += b2f_lo(u.z); a[5] += b2f_hi(u.z);
            a[6] += b2f_lo(u.w); a[7] += b2f_hi(u.w);
        }
        if (j < t && half == 0) {
            const uint4 u = ef4[(size_t)lst[j] * 16 + q];
            a[0] += b2f_lo(u.x); a[1] += b2f_hi(u.x);
            a[2] += b2f_lo(u.y); a[3] += b2f_hi(u.y);
            a[4] += b2f_lo(u.z); a[5] += b2f_hi(u.z);
            a[6] += b2f_lo(u.w); a[7] += b2f_hi(u.w);
        }
#pragma unroll
        for (int k = 0; k < 8; ++k) a[k] += __shfl_xor(a[k], 16);
        // both halves now hold the full sums: compute o on both
        const float dinv = Dinv[v];
        const float4 b0 = *(const float4*)&b[8 * q];
        const float4 b1 = *(const float4*)&b[8 * q + 4];
        float o[8];
        o[0] = a[0] * dinv + b0.x; o[1] = a[1] * dinv + b0.y;
        o[2] = a[2] * dinv + b0.z; o[3] = a[3] * dinv + b0.w;
        o[4] = a[4] * dinv + b1.x; o[5] = a[5] * dinv + b1.y;
        o[6] = a[6] * dinv + b1.z; o[7] = a[7] * dinv + b1.w;
        if (half == 0) {
            uint4 ov;
            ov.x = f2b(o[0]) | (f2b(o[1]) << 16);
            ov.y = f2b(o[2]) | (f2b(o[3]) << 16);
            ov.z = f2b(o[4]) | (f2b(o[5]) << 16);
            ov.w = f2b(o[6]) | (f2b(o[7]) << 16);
            oh[(size_t)v * 16 + q] = ov;
            *(float4*)&bl[sub][8 * q]     = make_float4(o[0], o[1], o[2], o[3]);
            *(float4*)&bl[sub][8 * q + 4] = make_float4(o[4], o[5], o[6], o[7]);
        } else {
            *(float4*)&bl[sub][132 + 8 * q] = make_float4(o[0] * o[0], o[1] * o[1],
                                                          o[2] * o[2], o[3] * o[3]);
            *(float4*)&bl[sub][136 + 8 * q] = make_float4(o[4] * o[4], o[5] * o[5],
                                                          o[6] * o[6], o[7] * o[7]);
        }
    } else {
        const float4 z4 = make_float4(0.f, 0.f, 0.f, 0.f);
        if (half == 0) {
            *(float4*)&bl[sub][8 * q] = z4;
            *(float4*)&bl[sub][8 * q + 4] = z4;
        } else {
            *(float4*)&bl[sub][132 + 8 * q] = z4;
            *(float4*)&bl[sub][136 + 8 * q] = z4;
        }
    }
    __syncthreads();
    const int col = (tid < 128) ? tid : (tid + 4);   // squares live at +4 rotation
    float s = 0.f;
#pragma unroll
    for (int i = 0; i < 8; ++i) s += bl[i][col];
    atomicAdd(&copies[(blockIdx.x & 63) * 256 + tid], s);
}

// ---- BN normalize + SiLU: reduce 64 sum-copies, read bf16 pre-BN, write f32 ----
__global__ __launch_bounds__(256) void bn_silu(const uint2* __restrict__ oh2,
                                               const float* __restrict__ copies,
                                               const float* __restrict__ gamma,
                                               const float* __restrict__ beta,
                                               float* __restrict__ out, int N) {
    __shared__ float sl[256];
    const int tid = threadIdx.x;
    float s = 0.f;
#pragma unroll 8
    for (int i = 0; i < 64; ++i) s += copies[i * 256 + tid];
    sl[tid] = s;
    __syncthreads();
    const int sub = tid >> 5;
    const int lane = tid & 31;
    const int c4 = lane * 4;
    const float invN = 1.0f / (float)N;
    float g[4], bb[4];
#pragma unroll
    for (int k = 0; k < 4; ++k) {
        const float mean = sl[c4 + k] * invN;
        float var = sl[128 + c4 + k] * invN - mean * mean;
        var = fmaxf(var, 0.f);
        const float istd = rsqrtf(var + 1e-5f);
        g[k] = gamma[c4 + k] * istd;
        bb[k] = beta[c4 + k] - mean * g[k];
    }
    for (int v = blockIdx.x * 8 + sub; v < N; v += gridDim.x * 8) {
        const uint2 u = oh2[(size_t)v * 32 + lane];
        float y[4];
        y[0] = b2f_lo(u.x); y[1] = b2f_hi(u.x);
        y[2] = b2f_lo(u.y); y[3] = b2f_hi(u.y);
        float4 o;
#pragma unroll
        for (int k = 0; k < 4; ++k) {
            const float z = y[k] * g[k] + bb[k];
            (&o.x)[k] = z / (1.f + __expf(-z));
        }
        *(float4*)&out[(size_t)v * CC + c4] = o;
    }
}

extern "C" void kernel_launch(void* const* d_in, const int* in_sizes, int n_in,
                              void* d_out, int out_size, void* d_ws, size_t ws_size,
                              hipStream_t stream) {
    const float* x     = (const float*)d_in[0];
    const int*   hidx  = (const int*)d_in[1];
    const float* hw    = (const float*)d_in[2];
    const float* W     = (const float*)d_in[3];
    const float* b     = (const float*)d_in[4];
    const float* gamma = (const float*)d_in[5];
    const float* beta  = (const float*)d_in[6];

    const int N   = in_sizes[0] / CC;   // 100000
    const int nnz = in_sizes[1] / 2;    // 1600000
    const int E   = in_sizes[2];        // 50000

    const int* nidx = hidx;
    const int* eidx = hidx + nnz;

    float* out = (float*)d_out;

    const int nbE = (E + FINE - 1) / FINE;   // 391
    const int nbV = (N + FINE - 1) / FINE;   // 782

    unsigned* ws      = (unsigned*)d_ws;
    unsigned* xh      = ws;                              // N*64 uints (bf16 x; reused as oh)
    unsigned* eraw    = xh + (size_t)N * 64;             // E*64
    unsigned* efeat   = eraw + (size_t)E * 64;           // E*64
    int2*     rowsE   = (int2*)(efeat + (size_t)E * 64); // E int2
    int2*     rowsV   = rowsE + E;                       // N int2
    float*    Dinv    = (float*)(rowsV + N);             // N floats
    float*    copies  = Dinv + N;                        // 64*256 floats
    int*      curE    = (int*)(copies + 64 * 256);       // nbE (relative)
    int*      curV    = curE + nbE;                      // nbV (relative)
    unsigned* binnedE = (unsigned*)(curV + nbV);         // nbE*CAPE
    unsigned* binnedV = binnedE + (size_t)nbE * CAPE;    // nbV*CAPV
    uintptr_t bfaddr  = (uintptr_t)(binnedV + (size_t)nbV * CAPV);
    uint4*    Bfrag   = (uint4*)((bfaddr + 15) & ~(uintptr_t)15);  // 2048 uint4

    // zero copies + relative cursors in one memset
    hipMemsetAsync(copies, 0, (64 * 256 + (size_t)nbE + nbV) * sizeof(int), stream);

    const int nbin = (nnz + BIN_TILE - 1) / BIN_TILE;   // 196
    const int ncvt = 256;
    prep<<<nbin + ncvt + 4, 512, 0, stream>>>(nidx, eidx, curE, curV, binnedE, binnedV,
                                              nnz, nbE, nbV, nbin, ncvt,
                                              (const float4*)x, (uint2*)xh, N * CC / 4,
                                              W, Bfrag);

    fill_all<<<nbE + nbV, 512, 0, stream>>>(curE, curV, binnedE, binnedV, hw,
                                            rowsE, rowsV, Dinv, E, N, nbE);

    gather_n2e<<<(E + 7) / 8, 256, 0, stream>>>(rowsE, binnedE, (const uint4*)xh,
                                                (uint4*)eraw, E);

    mm_mfma<<<(E + 63) / 64, 256, 0, stream>>>((const uint4*)eraw, Bfrag,
                                               (unsigned short*)efeat, E);

    // xh is dead after hop1 -> reuse as bf16 pre-BN output buffer
    gather_e2n_bn<<<(N + 7) / 8, 256, 0, stream>>>(rowsV, binnedV, (const uint4*)efeat,
                                                   Dinv, b, (uint4*)xh, copies, N);

    bn_silu<<<1024, 256, 0, stream>>>((const uint2*)xh, copies, gamma, beta, out, N);
}